// Round 2
// baseline (75.178 us; speedup 1.0000x reference)
//
#include <hip/hip_runtime.h>
#include <math.h>

#define CH 1
#define H 1024
#define NN 64
#define N_SSM 1024
#define SEQ_L 2048
#define TPB 128
#define LPT 16    // l-values per thread; SEQ_L / TPB == LPT

typedef float v2f __attribute__((ext_vector_type(2)));

__device__ __forceinline__ v2f lo2(const float4 f) { v2f r; r.x = f.x; r.y = f.y; return r; }
__device__ __forceinline__ v2f hi2(const float4 f) { v2f r; r.x = f.z; r.y = f.w; return r; }

__global__ __launch_bounds__(TPB) void sskd_kernel(
    const float* __restrict__ C_ri, const float* __restrict__ log_dt,
    const float* __restrict__ B_ri, const float* __restrict__ inv_A_real,
    const float* __restrict__ A_imag, float* __restrict__ out)
{
    const int h   = blockIdx.x;
    const int tid = threadIdx.x;

    // l = 16*tid + k = 256*t1 + 16*t0 + k.
    // Tables (float4 = {re_n0, re_n1, im_n0, im_n1} per n-pair):
    //   sU1[t1][m] = 2Ct      * w^(256 t1)   (seeds x(l0))
    //   sV1[t1][m] = 2Ct*dA   * w^(256 t1)   (seeds x(l0+1))
    //   sU8[t1][m] = 2Ct      * w^(256 t1+8) (seeds x(l0+8))
    //   sV8[t1][m] = 2Ct*dA   * w^(256 t1+8) (seeds x(l0+9))
    //   sT [t0][m] = w^(16 t0)
    //   sPQ[m]     = {p0,p1,q0,q1}; x_l = p*x_{l-1} - q*x_{l-2}
    // Row stride 33 float4 = 132 dwords -> rows 4 banks apart: <=2-way conflicts (free).
    __shared__ __align__(16) float4 sU1[8][33], sV1[8][33], sU8[8][33], sV8[8][33];
    __shared__ __align__(16) float4 sT[16][33];
    __shared__ __align__(16) float4 sPQ[32];
    __shared__ double sW8r[NN], sW8i[NN], sW16r[NN], sW16i[NN], sW256r[NN], sW256i[NN];
    __shared__ double sCtr[NN], sCti[NN], sCdr[NN], sCdi[NN];

    // ---- Stage A (one wave): per-n params + w^8 / w^16 / w^256, double-precision chain ----
    if (tid < NN) {
        const int n = tid;
        const double dt = exp((double)log_dt[h]);
        const double Ar = -exp((double)inv_A_real[h * NN + n]);
        const double Ai = (double)A_imag[h * NN + n];
        const double hr = 0.5 * Ar * dt, hi = 0.5 * Ai * dt;    // dtA/2
        const double den_r = 1.0 - hr, den_i = -hi;
        const double num_r = 1.0 + hr, num_i = hi;
        const double inv_den = 1.0 / (den_r * den_r + den_i * den_i);
        const double dAr = (num_r * den_r + num_i * den_i) * inv_den;
        const double dAi = (num_i * den_r - num_r * den_i) * inv_den;
        const int    bh = h % N_SSM;                            // rep==1 here, kept general
        const double Br = B_ri[(bh * NN + n) * 2 + 0];
        const double Bi = B_ri[(bh * NN + n) * 2 + 1];
        const double Cr = C_ri[(h * NN + n) * 2 + 0];
        const double Ci = C_ri[(h * NN + n) * 2 + 1];
        const double BCr = Br * Cr - Bi * Ci;
        const double BCi = Br * Ci + Bi * Cr;
        const double sc = 2.0 * dt * inv_den;                   // fold final 2*Re(..)
        const double ctr = (BCr * den_r + BCi * den_i) * sc;
        const double cti = (BCi * den_r - BCr * den_i) * sc;
        sCtr[n] = ctr; sCti[n] = cti;
        sCdr[n] = ctr * dAr - cti * dAi;                        // ct*dA
        sCdi[n] = ctr * dAi + cti * dAr;
        float* pqp = (float*)&sPQ[n >> 1];
        pqp[(n & 1)]     = (float)(2.0 * dAr);
        pqp[2 + (n & 1)] = (float)(dAr * dAr + dAi * dAi);      // |dA|^2 < 1
        // squaring chain (double): w^2..w^256
        double wr = dAr, wi = dAi, tr;
        tr = wr * wr - wi * wi; wi = 2.0 * wr * wi; wr = tr;    // w^2
        tr = wr * wr - wi * wi; wi = 2.0 * wr * wi; wr = tr;    // w^4
        tr = wr * wr - wi * wi; wi = 2.0 * wr * wi; wr = tr;    // w^8
        sW8r[n] = wr; sW8i[n] = wi;
        tr = wr * wr - wi * wi; wi = 2.0 * wr * wi; wr = tr;    // w^16
        sW16r[n] = wr; sW16i[n] = wi;
        tr = wr * wr - wi * wi; wi = 2.0 * wr * wi; wr = tr;    // w^32
        tr = wr * wr - wi * wi; wi = 2.0 * wr * wi; wr = tr;    // w^64
        tr = wr * wr - wi * wi; wi = 2.0 * wr * wi; wr = tr;    // w^128
        tr = wr * wr - wi * wi; wi = 2.0 * wr * wi; wr = tr;    // w^256
        sW256r[n] = wr; sW256i[n] = wi;
    }
    __syncthreads();

    // ---- Stage B (2 waves): fill tables; wave g handles half the rows ----
    {
        const int n = tid & 63;
        const int g = tid >> 6;        // wave-uniform, 0 or 1
        const int np = n >> 1, nc = n & 1;
        // T rows: t0 = 8g..8g+7, V = (w16)^(8g), chain * w16
        {
            const double ur = sW16r[n], ui = sW16i[n];
            double Vr = 1.0, Vi = 0.0;
            if (g) {
                double ar = ur, ai = ui, t;
                t = ar * ar - ai * ai; ai = 2.0 * ar * ai; ar = t;   // ^2
                t = ar * ar - ai * ai; ai = 2.0 * ar * ai; ar = t;   // ^4
                t = ar * ar - ai * ai; ai = 2.0 * ar * ai; ar = t;   // ^8
                Vr = ar; Vi = ai;
            }
            #pragma unroll
            for (int i = 0; i < 8; ++i) {
                float* bp = (float*)&sT[8 * g + i][np];
                bp[nc] = (float)Vr; bp[2 + nc] = (float)Vi;
                const double t = Vr * ur - Vi * ui; Vi = Vr * ui + Vi * ur; Vr = t;
            }
        }
        // U/V rows: t1 = 4g..4g+3, W = (w256)^(4g), chain * w256
        {
            const double wr = sW256r[n], wi = sW256i[n];
            const double er = sW8r[n],  ei = sW8i[n];
            const double ctr = sCtr[n], cti = sCti[n];
            const double cdr = sCdr[n], cdi = sCdi[n];
            double Wr = 1.0, Wi = 0.0;
            if (g) {
                double ar = wr, ai = wi, t;
                t = ar * ar - ai * ai; ai = 2.0 * ar * ai; ar = t;   // ^2
                t = ar * ar - ai * ai; ai = 2.0 * ar * ai; ar = t;   // ^4
                Wr = ar; Wi = ai;
            }
            #pragma unroll
            for (int i = 0; i < 4; ++i) {
                const int t1 = 4 * g + i;
                const double u1r = ctr * Wr - cti * Wi, u1i = ctr * Wi + cti * Wr;
                const double v1r = cdr * Wr - cdi * Wi, v1i = cdr * Wi + cdi * Wr;
                const double u8r = u1r * er - u1i * ei, u8i = u1r * ei + u1i * er;
                const double v8r = v1r * er - v1i * ei, v8i = v1r * ei + v1i * er;
                float* a = (float*)&sU1[t1][np]; a[nc] = (float)u1r; a[2 + nc] = (float)u1i;
                float* b = (float*)&sV1[t1][np]; b[nc] = (float)v1r; b[2 + nc] = (float)v1i;
                float* c = (float*)&sU8[t1][np]; c[nc] = (float)u8r; c[2 + nc] = (float)u8i;
                float* d = (float*)&sV8[t1][np]; d[nc] = (float)v8r; d[2 + nc] = (float)v8i;
                const double t = Wr * wr - Wi * wi; Wi = Wr * wi + Wi * wr; Wr = t;
            }
        }
    }
    __syncthreads();

    // ---- Main loop: 6 ds_read_b128 + ~48 pk-ops per m (2 n's, 16 l's),
    //      two independent depth-6 chains, register double-buffered loads ----
    const int t1 = tid >> 4;
    const int t0 = tid & 15;

    v2f acc[LPT];
    #pragma unroll
    for (int k = 0; k < LPT; ++k) acc[k] = (v2f)(0.0f);

    float4 u1 = sU1[t1][0], v1 = sV1[t1][0], u8 = sU8[t1][0], v8 = sV8[t1][0];
    float4 tt = sT[t0][0],  pq = sPQ[0];

    #pragma unroll 2
    for (int m = 0; m < NN / 2; ++m) {
        const int mn = (m + 1) & 31;                 // branchless prefetch (wraps once)
        const float4 u1n = sU1[t1][mn], v1n = sV1[t1][mn];
        const float4 u8n = sU8[t1][mn], v8n = sV8[t1][mn];
        const float4 ttn = sT[t0][mn],  pqn = sPQ[mn];

        const v2f br = lo2(tt), bi = hi2(tt);
        const v2f p  = lo2(pq), q  = hi2(pq);

        v2f xA2 = lo2(u1) * br - hi2(u1) * bi;       // x(l0)
        v2f xA1 = lo2(v1) * br - hi2(v1) * bi;       // x(l0+1)
        v2f xB2 = lo2(u8) * br - hi2(u8) * bi;       // x(l0+8)
        v2f xB1 = lo2(v8) * br - hi2(v8) * bi;       // x(l0+9)
        acc[0] += xA2; acc[1] += xA1;
        acc[8] += xB2; acc[9] += xB1;
        #pragma unroll
        for (int k = 2; k < 8; ++k) {
            const v2f xn = p * xA1 - q * xA2;        // v_pk_mul + v_pk_fma
            acc[k] += xn;     xA2 = xA1; xA1 = xn;
            const v2f yn = p * xB1 - q * xB2;
            acc[8 + k] += yn; xB2 = xB1; xB1 = yn;
        }

        u1 = u1n; v1 = v1n; u8 = u8n; v8 = v8n; tt = ttn; pq = pqn;
    }

    float4 o;
    float4* op = (float4*)(out + (size_t)h * SEQ_L + tid * LPT);
    o.x = acc[0].x  + acc[0].y;  o.y = acc[1].x  + acc[1].y;
    o.z = acc[2].x  + acc[2].y;  o.w = acc[3].x  + acc[3].y;
    op[0] = o;
    o.x = acc[4].x  + acc[4].y;  o.y = acc[5].x  + acc[5].y;
    o.z = acc[6].x  + acc[6].y;  o.w = acc[7].x  + acc[7].y;
    op[1] = o;
    o.x = acc[8].x  + acc[8].y;  o.y = acc[9].x  + acc[9].y;
    o.z = acc[10].x + acc[10].y; o.w = acc[11].x + acc[11].y;
    op[2] = o;
    o.x = acc[12].x + acc[12].y; o.y = acc[13].x + acc[13].y;
    o.z = acc[14].x + acc[14].y; o.w = acc[15].x + acc[15].y;
    op[3] = o;
}

extern "C" void kernel_launch(void* const* d_in, const int* in_sizes, int n_in,
                              void* d_out, int out_size, void* d_ws, size_t ws_size,
                              hipStream_t stream) {
    const float* C_ri       = (const float*)d_in[0];
    const float* log_dt     = (const float*)d_in[1];
    const float* B_ri       = (const float*)d_in[2];
    const float* inv_A_real = (const float*)d_in[3];
    const float* A_imag     = (const float*)d_in[4];
    float* out = (float*)d_out;

    sskd_kernel<<<dim3(H), dim3(TPB), 0, stream>>>(
        C_ri, log_dt, B_ri, inv_A_real, A_imag, out);
}

// Round 3
// 74.642 us; speedup vs baseline: 1.0072x; 1.0072x over previous
//
#include <hip/hip_runtime.h>
#include <math.h>

#define CH 1
#define H 1024
#define NN 64
#define N_SSM 1024
#define SEQ_L 2048
#define TPB 512
#define LPT 16     // l-values per thread (one depth-16 recurrence chain)
#define NSLICE 4   // n-sum split across quad lanes
#define MPT 8      // m-iterations per thread = (NN/2)/NSLICE

typedef float v2f __attribute__((ext_vector_type(2)));

static __device__ __forceinline__ v2f lo2(const float4 f){ v2f r; r.x=f.x; r.y=f.y; return r; }
static __device__ __forceinline__ v2f hi2(const float4 f){ v2f r; r.x=f.z; r.y=f.w; return r; }

// quad_perm lane swaps on the VALU (DPP) -- no LDS traffic
static __device__ __forceinline__ float qswap1(float x){   // lanes [1,0,3,2]
    return __builtin_bit_cast(float,
        __builtin_amdgcn_mov_dpp(__builtin_bit_cast(int,x), 0xB1, 0xF, 0xF, true));
}
static __device__ __forceinline__ float qswap2(float x){   // lanes [2,3,0,1]
    return __builtin_bit_cast(float,
        __builtin_amdgcn_mov_dpp(__builtin_bit_cast(int,x), 0x4E, 0xF, 0xF, true));
}

__global__ __launch_bounds__(TPB) void sskd_kernel(
    const float* __restrict__ C_ri, const float* __restrict__ log_dt,
    const float* __restrict__ B_ri, const float* __restrict__ inv_A_real,
    const float* __restrict__ A_imag, float* __restrict__ out)
{
    const int h   = blockIdx.x;
    const int tid = threadIdx.x;

    // l = 16*u + k, u = tid>>2 = 16*u1 + u0  (u1 = wave id, u0 = lane>>2)
    // Tables (float4 = {re_n0, re_n1, im_n0, im_n1} per n-pair m):
    //   sU1[u1][m] = 2Ct      * w^(256 u1)
    //   sV1[u1][m] = 2Ct*dA   * w^(256 u1)
    //   sT [u0][m] = w^(16 u0)
    //   sPQ[m]     = {p0,p1,q0,q1};  x_l = p*x_{l-1} - q*x_{l-2}
    // Row stride 33 float4 keeps row starts 4 banks apart.
    __shared__ __align__(16) float4 sU1[8][33], sV1[8][33], sT[16][33], sPQ[32];
    __shared__ double dW16r[NN], dW16i[NN], dW256r[NN], dW256i[NN],
                      dCtr[NN],  dCti[NN],  dCdr[NN],  dCdi[NN];

    // ---- Stage A (one wave): per-n params + w^16 / w^256, f64 squaring chain ----
    if (tid < NN) {
        const int n = tid;
        const double dt = exp((double)log_dt[h]);
        const double Ar = -exp((double)inv_A_real[h * NN + n]);
        const double Ai = (double)A_imag[h * NN + n];
        const double hr = 0.5 * Ar * dt, hi = 0.5 * Ai * dt;    // dtA/2
        const double den_r = 1.0 - hr, den_i = -hi;
        const double inv_den = 1.0 / (den_r * den_r + den_i * den_i);
        const double dAr = ((1.0 + hr) * den_r + hi * den_i) * inv_den;
        const double dAi = (hi * den_r - (1.0 + hr) * den_i) * inv_den;
        const int    bh = h % N_SSM;                            // rep==1, kept general
        const double Br = B_ri[(bh * NN + n) * 2 + 0];
        const double Bi = B_ri[(bh * NN + n) * 2 + 1];
        const double Cr = C_ri[(h * NN + n) * 2 + 0];
        const double Ci = C_ri[(h * NN + n) * 2 + 1];
        const double BCr = Br * Cr - Bi * Ci;
        const double BCi = Br * Ci + Bi * Cr;
        const double sc = 2.0 * dt * inv_den;                   // fold final 2*Re(..)
        const double ctr = (BCr * den_r + BCi * den_i) * sc;
        const double cti = (BCi * den_r - BCr * den_i) * sc;
        dCtr[n] = ctr; dCti[n] = cti;
        dCdr[n] = ctr * dAr - cti * dAi;                        // ct*dA
        dCdi[n] = ctr * dAi + cti * dAr;
        float* pqp = (float*)&sPQ[n >> 1];
        pqp[(n & 1)]     = (float)(2.0 * dAr);
        pqp[2 + (n & 1)] = (float)(dAr * dAr + dAi * dAi);      // |dA|^2 < 1
        double wr = dAr, wi = dAi, tr;
        tr = wr*wr - wi*wi; wi = 2.0*wr*wi; wr = tr;            // w^2
        tr = wr*wr - wi*wi; wi = 2.0*wr*wi; wr = tr;            // w^4
        tr = wr*wr - wi*wi; wi = 2.0*wr*wi; wr = tr;            // w^8
        tr = wr*wr - wi*wi; wi = 2.0*wr*wi; wr = tr;            // w^16
        dW16r[n] = wr; dW16i[n] = wi;
        tr = wr*wr - wi*wi; wi = 2.0*wr*wi; wr = tr;            // w^32
        tr = wr*wr - wi*wi; wi = 2.0*wr*wi; wr = tr;            // w^64
        tr = wr*wr - wi*wi; wi = 2.0*wr*wi; wr = tr;            // w^128
        tr = wr*wr - wi*wi; wi = 2.0*wr*wi; wr = tr;            // w^256
        dW256r[n] = wr; dW256i[n] = wi;
    }
    __syncthreads();

    // ---- Stage B (8 waves): wave g fills T rows {2g,2g+1} and U/V row g ----
    {
        const int n = tid & 63;
        const int g = tid >> 6;
        const int np = n >> 1, nc = n & 1;
        // T rows: V = w16^(2g), chain * w16
        {
            const double ur = dW16r[n], ui = dW16i[n];
            const double a2r = ur*ur - ui*ui,     a2i = 2.0*ur*ui;      // w16^2
            const double a4r = a2r*a2r - a2i*a2i, a4i = 2.0*a2r*a2i;    // w16^4
            double Vr = 1.0, Vi = 0.0;
            if (g & 1) { Vr = a2r; Vi = a2i; }
            if (g & 2) { const double t = Vr*a4r - Vi*a4i; Vi = Vr*a4i + Vi*a4r; Vr = t; }
            if (g & 4) { const double a8r = a4r*a4r - a4i*a4i, a8i = 2.0*a4r*a4i;
                         const double t = Vr*a8r - Vi*a8i; Vi = Vr*a8i + Vi*a8r; Vr = t; }
            #pragma unroll
            for (int i = 0; i < 2; ++i) {
                float* bp = (float*)&sT[2*g + i][np];
                bp[nc] = (float)Vr; bp[2 + nc] = (float)Vi;
                const double t = Vr*ur - Vi*ui; Vi = Vr*ui + Vi*ur; Vr = t;
            }
        }
        // U/V row g: W = w256^g
        {
            const double wr = dW256r[n], wi = dW256i[n];
            const double b2r = wr*wr - wi*wi,     b2i = 2.0*wr*wi;      // w256^2
            const double b4r = b2r*b2r - b2i*b2i, b4i = 2.0*b2r*b2i;    // w256^4
            double Wr = 1.0, Wi = 0.0;
            if (g & 1) { Wr = wr; Wi = wi; }
            if (g & 2) { const double t = Wr*b2r - Wi*b2i; Wi = Wr*b2i + Wi*b2r; Wr = t; }
            if (g & 4) { const double t = Wr*b4r - Wi*b4i; Wi = Wr*b4i + Wi*b4r; Wr = t; }
            const double ctr = dCtr[n], cti = dCti[n], cdr = dCdr[n], cdi = dCdi[n];
            float* a = (float*)&sU1[g][np];
            a[nc] = (float)(ctr*Wr - cti*Wi); a[2 + nc] = (float)(ctr*Wi + cti*Wr);
            float* b = (float*)&sV1[g][np];
            b[nc] = (float)(cdr*Wr - cdi*Wi); b[2 + nc] = (float)(cdr*Wi + cdi*Wr);
        }
    }
    __syncthreads();

    // ---- Main loop: 8 m-iters, 4 ds_read_b128 + ~48 pk-ops each ----
    const int s  = tid & 3;          // n-slice (quad lane)
    const int u0 = (tid >> 2) & 15;  // T row
    const int w  = tid >> 6;         // U row (wave-uniform)

    v2f acc[LPT];
    #pragma unroll
    for (int k = 0; k < LPT; ++k) acc[k] = (v2f)(0.0f);

    const int M0 = MPT * s;
    #pragma unroll 2
    for (int j = 0; j < MPT; ++j) {
        const int m = M0 + j;
        const float4 A  = sU1[w][m];
        const float4 Bv = sV1[w][m];
        const float4 Tt = sT[u0][m];
        const float4 Pq = sPQ[m];
        const v2f br = lo2(Tt), bi = hi2(Tt);
        const v2f p  = lo2(Pq), qq = hi2(Pq);

        v2f x2 = lo2(A)  * br - hi2(A)  * bi;   // x(l0)
        v2f x1 = lo2(Bv) * br - hi2(Bv) * bi;   // x(l0+1)
        acc[0] += x2; acc[1] += x1;
        #pragma unroll
        for (int k = 2; k < LPT; ++k) {
            const v2f xn = p * x1 - qq * x2;    // v_pk_mul + v_pk_fma
            acc[k] += xn;
            x2 = x1; x1 = xn;
        }
    }

    // ---- Fold n0+n1, reduce across the 4 slice lanes via DPP, store ----
    float r[LPT];
    #pragma unroll
    for (int k = 0; k < LPT; ++k) {
        float v = acc[k].x + acc[k].y;
        v += qswap1(v);
        v += qswap2(v);
        r[k] = v;                                // full quad sum in every lane
    }

    float4 o;
    if      (s == 0) { o.x = r[0];  o.y = r[1];  o.z = r[2];  o.w = r[3];  }
    else if (s == 1) { o.x = r[4];  o.y = r[5];  o.z = r[6];  o.w = r[7];  }
    else if (s == 2) { o.x = r[8];  o.y = r[9];  o.z = r[10]; o.w = r[11]; }
    else             { o.x = r[12]; o.y = r[13]; o.z = r[14]; o.w = r[15]; }
    const int u = tid >> 2;
    *(float4*)(out + (size_t)h * SEQ_L + u * LPT + 4 * s) = o;
}

extern "C" void kernel_launch(void* const* d_in, const int* in_sizes, int n_in,
                              void* d_out, int out_size, void* d_ws, size_t ws_size,
                              hipStream_t stream) {
    const float* C_ri       = (const float*)d_in[0];
    const float* log_dt     = (const float*)d_in[1];
    const float* B_ri       = (const float*)d_in[2];
    const float* inv_A_real = (const float*)d_in[3];
    const float* A_imag     = (const float*)d_in[4];
    float* out = (float*)d_out;

    sskd_kernel<<<dim3(H), dim3(TPB), 0, stream>>>(
        C_ri, log_dt, B_ri, inv_A_real, A_imag, out);
}